// Round 2
// baseline (118.711 us; speedup 1.0000x reference)
//
#include <hip/hip_runtime.h>

// QTT 3D sampling, round 11: move ALL GEMM work into dense tables.
//   out[i] = P3[a_i] · (C4[d4_i] · T[q_i])  -- reassociate so the C4
//   contraction is sample-independent:
//     U[d4][q][k] = sum_s5 C4t[d4][s5][k] * T[q][s5]      (4096x256 table)
//   K0 (96 blocks):  blocks 0-63  T[q][s5] = C5·(C6·C7)   (512x256 table)
//                    blocks 64-95 C4t[d4][s5][k] = C4[k][d4][s5] (transpose)
//   K1 (1024 blocks): blocks 0-511  P3 = C0·C1·C2·C3 (block=(d0,d2,d3), 8 d1
//                     rows built in-LDS, K=256 GEMM vs C3[d3])
//                     blocks 512-1023 U (block=(d4,qtile), A=T rows staged
//                     async, K=256 GEMM over s5 vs C4t[d4])
//                     Both use the barrier-free per-wave K-split GEMM:
//                     wave w owns K in [64w,64w+64), private dbuf B stage,
//                     counted vmcnt(4), 4-way cross-wave reduce at the end.
//   K2 (n/4 blocks): out[i] = dot256(P3[a_i], U[d4_i*512+q_i]) -- one wave
//                    per sample, 2 float4 loads + shfl reduce. No sort.
// Core shapes: (r_l, 8, r_{l+1}), ranks 1,8,64,256,256,256,64,8,1.
// C_l[k][d][s] at C_l[k*8*r_out + d*r_out + s].

typedef unsigned int u32;

__device__ __forceinline__ void async_load16(const float* g, float* l) {
    __builtin_amdgcn_global_load_lds(
        (const __attribute__((address_space(1))) u32*)g,
        (__attribute__((address_space(3))) u32*)l, 16, 0, 0);
}
__device__ __forceinline__ void fma4(float4& c, float a, const float4& b) {
    c.x = fmaf(a, b.x, c.x); c.y = fmaf(a, b.y, c.y);
    c.z = fmaf(a, b.z, c.z); c.w = fmaf(a, b.w, c.w);
}
__device__ __forceinline__ int digit_of(int x, int y, int z, int sh) {
    return 4*((x>>sh)&1) + 2*((y>>sh)&1) + ((z>>sh)&1);
}

// Barrier-free K-split GEMM: 8 rows (As) x 256 cols, K=256 split 64/wave.
// Cd: B base, row k at Cd + k*rowStride. Caller must have prefetched this
// wave's chunk-0 (4 rows) into BsF[wv*2048 + 0..1023] and __syncthreads()'d.
// Ends with cross-wave reduction and coalesced store of 8 rows to
// outP[(rowBase + r*rowStep)*256 + ...].
__device__ __forceinline__ void kgemm_reduce_store(
    const float* __restrict__ Cd, int rowStride,
    const float (*As)[260], float* BsF,
    float* __restrict__ outP, int rowBase, int rowStep,
    int ln, int wv)
{
    const int kbase = wv * 64;
    float4 acc[8];
#pragma unroll
    for (int r = 0; r < 8; ++r) acc[r] = make_float4(0,0,0,0);

#pragma unroll 1
    for (int s = 0; s < 16; ++s) {
        if (s < 15) {
            const int nb = (s + 1) & 1;
            const int ko = kbase + (s + 1) * 4;
#pragma unroll
            for (int j = 0; j < 4; ++j)
                async_load16(Cd + (size_t)(ko + j)*rowStride + ln*4,
                             BsF + wv*2048 + nb*1024 + j*256 + ln*4);
            asm volatile("s_waitcnt vmcnt(4)" ::: "memory");
        } else {
            asm volatile("s_waitcnt vmcnt(0)" ::: "memory");
        }
        __builtin_amdgcn_sched_barrier(0);
        const int cb = s & 1, kb = kbase + s * 4;
        const float* Bp = BsF + wv*2048 + cb*1024;
        const float4 b0v = *(const float4*)(Bp +   0 + ln*4);
        const float4 b1v = *(const float4*)(Bp + 256 + ln*4);
        const float4 b2v = *(const float4*)(Bp + 512 + ln*4);
        const float4 b3v = *(const float4*)(Bp + 768 + ln*4);
#pragma unroll
        for (int r = 0; r < 8; ++r) {
            const float4 a = *(const float4*)&As[r][kb];
            fma4(acc[r], a.x, b0v); fma4(acc[r], a.y, b1v);
            fma4(acc[r], a.z, b2v); fma4(acc[r], a.w, b3v);
        }
    }

    // cross-wave K reduction through the (now dead) Bs region
    {
        float* my = BsF + wv * 2048;
#pragma unroll
        for (int r = 0; r < 8; ++r)
            *(float4*)(my + r*256 + ln*4) = acc[r];
    }
    __syncthreads();
#pragma unroll
    for (int i = 0; i < 2; ++i) {
        const int r = wv*2 + i;
        float4 v        = *(const float4*)(BsF +        r*256 + ln*4);
        const float4 p1 = *(const float4*)(BsF + 2048 + r*256 + ln*4);
        const float4 p2 = *(const float4*)(BsF + 4096 + r*256 + ln*4);
        const float4 p3 = *(const float4*)(BsF + 6144 + r*256 + ln*4);
        v.x += p1.x + p2.x + p3.x; v.y += p1.y + p2.y + p3.y;
        v.z += p1.z + p2.z + p3.z; v.w += p1.w + p2.w + p3.w;
        *(float4*)(outP + (size_t)(rowBase + r*rowStep)*256 + ln*4) = v;
    }
}

// ---------------- K0: T table + C4 transpose ---------------------------------
__global__ __launch_bounds__(256, 4) void prep_kernel(
    const float* __restrict__ C4, const float* __restrict__ C5,
    const float* __restrict__ C6, const float* __restrict__ C7,
    float* __restrict__ T, float* __restrict__ C4t)
{
    const int t = threadIdx.x;
    const int bx = blockIdx.x;

    if (bx < 64) {
        // ---- T table: block = (d5, d6), all 8 d7; thread t = s5 ----
        __shared__ float S6s[8][64];
        const int d5 = bx >> 3, d6 = bx & 7;
#pragma unroll
        for (int j = 0; j < 2; ++j) {
            const int idx = t + 256*j, d7 = idx >> 6, s = idx & 63;
            float acc = 0.f;
#pragma unroll
            for (int jj = 0; jj < 8; ++jj)
                acc = fmaf(C6[s*64 + d6*8 + jj], C7[jj*8 + d7], acc);
            S6s[d7][s] = acc;
        }
        __syncthreads();
        float4 creg[16];
#pragma unroll
        for (int s4 = 0; s4 < 16; ++s4)
            creg[s4] = *(const float4*)(C5 + (size_t)t*512 + d5*64 + s4*4);
#pragma unroll 1
        for (int d7 = 0; d7 < 8; ++d7) {
            float acc = 0.f;
#pragma unroll
            for (int s4 = 0; s4 < 16; ++s4) {
                const float4 a = creg[s4];
                const float4 b = *(const float4*)&S6s[d7][s4*4];
                acc = fmaf(a.x, b.x, acc); acc = fmaf(a.y, b.y, acc);
                acc = fmaf(a.z, b.z, acc); acc = fmaf(a.w, b.w, acc);
            }
            T[(size_t)((d5*8 + d6)*8 + d7)*256 + t] = acc;
        }
    } else {
        // ---- C4t[d4][s5][k] = C4[k][d4][s5]; thread t = k ----
        const int cb = bx - 64;
        const int d4 = cb >> 2, s5q = cb & 3;
#pragma unroll 8
        for (int j = 0; j < 64; ++j) {
            const int s5 = s5q*64 + j;
            C4t[(size_t)d4*65536 + (size_t)s5*256 + t] =
                C4[(size_t)t*2048 + d4*256 + s5];
        }
    }
}

// ---------------- K1: dense P3 table + dense U table -------------------------
__global__ __launch_bounds__(256, 3) void tables_kernel(
    const float* __restrict__ C0, const float* __restrict__ C1,
    const float* __restrict__ C2, const float* __restrict__ C3,
    const float* __restrict__ T, const float* __restrict__ C4t,
    float* __restrict__ P3, float* __restrict__ U)
{
    __shared__ __align__(16) struct {
        float v64[8][64]; float As[8][260]; float Bs[4][2][4][256];
    } u;
    const int t = threadIdx.x;
    const int ln = t & 63, wv = t >> 6;
    const int bx = blockIdx.x;
    float* BsF = &u.Bs[0][0][0][0];
    const int kbase = wv * 64;

    if (bx < 512) {
        // ---- P3 block: (d0, d2, d3); rows = 8 d1 values ----
        const int d3 = bx & 7, d2 = (bx >> 3) & 7, d0 = bx >> 6;
        const float* Cd = C3 + d3 * 256;      // row k at Cd + k*2048

        // prefetch this wave's chunk-0 B rows
#pragma unroll
        for (int j = 0; j < 4; ++j)
            async_load16(Cd + (size_t)(kbase + j)*2048 + ln*4,
                         BsF + wv*2048 + j*256 + ln*4);

        // v64[d1][c] = sum_r C0[d0,r] * C1[r, d1, c]
#pragma unroll
        for (int j = 0; j < 2; ++j) {
            const int idx = t + 256*j, d1 = idx >> 6, c = idx & 63;
            float acc = 0.f;
#pragma unroll
            for (int r = 0; r < 8; ++r)
                acc = fmaf(C0[d0*8 + r], C1[r*512 + d1*64 + c], acc);
            u.v64[d1][c] = acc;
        }
        __syncthreads();

        // As[d1][k] = sum_j v64[d1][j] * C2[j, d2, k]; wave builds d1=wv*2+{0,1}
        {
            float4 accA0 = make_float4(0,0,0,0), accA1 = make_float4(0,0,0,0);
#pragma unroll 8
            for (int j = 0; j < 64; ++j) {
                const float4 c2 = *(const float4*)(C2 + (size_t)j*2048 + d2*256 + ln*4);
                fma4(accA0, u.v64[wv*2 + 0][j], c2);
                fma4(accA1, u.v64[wv*2 + 1][j], c2);
            }
            *(float4*)&u.As[wv*2 + 0][ln*4] = accA0;
            *(float4*)&u.As[wv*2 + 1][ln*4] = accA1;
        }
        __syncthreads();                      // As + everyone's chunk0 ready

        kgemm_reduce_store(Cd, 2048, u.As, BsF,
                           P3, d0*512 + d2*8 + d3, 64, ln, wv);
    } else {
        // ---- U block: (d4, qtile); rows = q = qtile*8 + 0..7 ----
        const int ub = bx - 512;
        const int qtile = ub & 63, d4 = ub >> 6;
        const float* Cd = C4t + (size_t)d4*65536; // row s5 at Cd + s5*256

        // prefetch this wave's chunk-0 B rows
#pragma unroll
        for (int j = 0; j < 4; ++j)
            async_load16(Cd + (size_t)(kbase + j)*256 + ln*4,
                         BsF + wv*2048 + j*256 + ln*4);
        // stage A rows from T: wave wv stages rows wv*2, wv*2+1
#pragma unroll
        for (int i = 0; i < 2; ++i) {
            const int r = wv*2 + i;
            async_load16(T + (size_t)(qtile*8 + r)*256 + ln*4, &u.As[r][ln*4]);
        }
        __syncthreads();                      // As + everyone's chunk0 ready

        kgemm_reduce_store(Cd, 256, u.As, BsF,
                           U, d4*512 + qtile*8, 1, ln, wv);
    }
}

// ---------------- K2: per-sample dot(P3 row, U row) --------------------------
__global__ __launch_bounds__(256) void final_kernel(
    const float* __restrict__ P3, const float* __restrict__ U,
    const int* __restrict__ coords, int n, float* __restrict__ out)
{
    const int ln = threadIdx.x & 63, wv = threadIdx.x >> 6;
    const int s = blockIdx.x * 4 + wv;
    if (s >= n) return;
    const int x = coords[3*s], y = coords[3*s+1], z = coords[3*s+2];
    const int a  = digit_of(x,y,z,7)*512 + digit_of(x,y,z,6)*64
                 + digit_of(x,y,z,5)*8  + digit_of(x,y,z,4);
    const int d4 = digit_of(x,y,z,3);
    const int q  = digit_of(x,y,z,2)*64 + digit_of(x,y,z,1)*8
                 + digit_of(x,y,z,0);
    const float4 p4 = *(const float4*)(P3 + (size_t)a*256 + ln*4);
    const float4 u4 = *(const float4*)(U + (size_t)(d4*512 + q)*256 + ln*4);
    float p = fmaf(p4.x, u4.x, fmaf(p4.y, u4.y, fmaf(p4.z, u4.z, p4.w*u4.w)));
    p += __shfl_xor(p, 1);
    p += __shfl_xor(p, 2);
    p += __shfl_xor(p, 4);
    p += __shfl_xor(p, 8);
    p += __shfl_xor(p, 16);
    p += __shfl_xor(p, 32);
    if (ln == 0) out[s] = p;
}

extern "C" void kernel_launch(void* const* d_in, const int* in_sizes, int n_in,
                              void* d_out, int out_size, void* d_ws, size_t ws_size,
                              hipStream_t stream) {
    const float* C0 = (const float*)d_in[0];
    const float* C1 = (const float*)d_in[1];
    const float* C2 = (const float*)d_in[2];
    const float* C3 = (const float*)d_in[3];
    const float* C4 = (const float*)d_in[4];
    const float* C5 = (const float*)d_in[5];
    const float* C6 = (const float*)d_in[6];
    const float* C7 = (const float*)d_in[7];
    const int* coords = (const int*)d_in[8];
    float* out = (float*)d_out;

    const int n = in_sizes[8] / 3;

    // workspace (~11 MB)
    float* P3  = (float*)d_ws;                 // 4096*256
    float* U   = P3  + 4096*256;               // 4096*256
    float* Tt  = U   + 4096*256;               // 512*256
    float* C4t = Tt  + 512*256;                // 8*256*256

    prep_kernel<<<96, 256, 0, stream>>>(C4, C5, C6, C7, Tt, C4t);
    tables_kernel<<<1024, 256, 0, stream>>>(C0, C1, C2, C3, Tt, C4t, P3, U);
    final_kernel<<<(n + 3) / 4, 256, 0, stream>>>(P3, U, coords, n, out);
}

// Round 3
// 113.435 us; speedup vs baseline: 1.0465x; 1.0465x over previous
//
#include <hip/hip_runtime.h>

// QTT 3D sampling, round 12: M=16 blocks, single occupancy round.
//   out[i] = P3[a_i] · U[d4_i*512 + q_i]   (reassociated; see round 11)
//   K0 (96 blocks):  blocks 0-63  T[q][s5] = C5·(C6·C7)   (512x256)
//                    blocks 64-95 C4t[d4][s5][k] = C4[k][d4][s5]
//   K1 (512 blocks): blocks 0-255   P3 = C0·C1·C2·C3, block=(d0,d2pair,d3),
//                                   16 rows (d2sub,d1) built in-LDS
//                    blocks 256-511 U[d4][q][k] = sum_s5 T[q][s5]*C4t[d4][s5][k],
//                                   block=(d4,qtile16), A = 16 T rows (async)
//     Barrier-free per-wave K-split GEMM: wave w owns K in [64w,64w+64),
//     private dbuf B stage, counted vmcnt(4), no main-loop barriers;
//     two-phase 4-way cross-wave reduce through the dead Bs region.
//   K2 (512 blocks): out[i] = dot256(P3[a_i], U[...]), 2 samples per wave.
// Core shapes: (r_l, 8, r_{l+1}), ranks 1,8,64,256,256,256,64,8,1.
// C_l[k][d][s] at C_l[k*8*r_out + d*r_out + s].

typedef unsigned int u32;

__device__ __forceinline__ void async_load16(const float* g, float* l) {
    __builtin_amdgcn_global_load_lds(
        (const __attribute__((address_space(1))) u32*)g,
        (__attribute__((address_space(3))) u32*)l, 16, 0, 0);
}
__device__ __forceinline__ void fma4(float4& c, float a, const float4& b) {
    c.x = fmaf(a, b.x, c.x); c.y = fmaf(a, b.y, c.y);
    c.z = fmaf(a, b.z, c.z); c.w = fmaf(a, b.w, c.w);
}
__device__ __forceinline__ int digit_of(int x, int y, int z, int sh) {
    return 4*((x>>sh)&1) + 2*((y>>sh)&1) + ((z>>sh)&1);
}

// ---------------- K0: T table + C4 transpose ---------------------------------
__global__ __launch_bounds__(256, 4) void prep_kernel(
    const float* __restrict__ C4, const float* __restrict__ C5,
    const float* __restrict__ C6, const float* __restrict__ C7,
    float* __restrict__ T, float* __restrict__ C4t)
{
    const int t = threadIdx.x;
    const int bx = blockIdx.x;

    if (bx < 64) {
        // ---- T table: block = (d5, d6), all 8 d7; thread t = s5 ----
        __shared__ float S6s[8][64];
        const int d5 = bx >> 3, d6 = bx & 7;
#pragma unroll
        for (int j = 0; j < 2; ++j) {
            const int idx = t + 256*j, d7 = idx >> 6, s = idx & 63;
            float acc = 0.f;
#pragma unroll
            for (int jj = 0; jj < 8; ++jj)
                acc = fmaf(C6[s*64 + d6*8 + jj], C7[jj*8 + d7], acc);
            S6s[d7][s] = acc;
        }
        __syncthreads();
        float4 creg[16];
#pragma unroll
        for (int s4 = 0; s4 < 16; ++s4)
            creg[s4] = *(const float4*)(C5 + (size_t)t*512 + d5*64 + s4*4);
#pragma unroll 1
        for (int d7 = 0; d7 < 8; ++d7) {
            float acc = 0.f;
#pragma unroll
            for (int s4 = 0; s4 < 16; ++s4) {
                const float4 a = creg[s4];
                const float4 b = *(const float4*)&S6s[d7][s4*4];
                acc = fmaf(a.x, b.x, acc); acc = fmaf(a.y, b.y, acc);
                acc = fmaf(a.z, b.z, acc); acc = fmaf(a.w, b.w, acc);
            }
            T[(size_t)((d5*8 + d6)*8 + d7)*256 + t] = acc;
        }
    } else {
        // ---- C4t[d4][s5][k] = C4[k][d4][s5]; thread t = k ----
        const int cb = bx - 64;
        const int d4 = cb >> 2, s5q = cb & 3;
#pragma unroll 8
        for (int j = 0; j < 64; ++j) {
            const int s5 = s5q*64 + j;
            C4t[(size_t)d4*65536 + (size_t)s5*256 + t] =
                C4[(size_t)t*2048 + d4*256 + s5];
        }
    }
}

// Barrier-free K-split GEMM, M=16 rows x 256 cols, K=256 split 64/wave.
// Caller prefetched this wave's chunk-0 into BsF[wv*2048..] and staged As,
// then __syncthreads()'d. Output row for r: rowBase + mulLo*(r&7) + 8*(r>>3).
__device__ __forceinline__ void kgemm16(
    const float* __restrict__ Cd, int rowStride,
    const float (*As)[260], float* BsF,
    float* __restrict__ outP, int rowBase, int mulLo,
    int ln, int wv)
{
    const int kbase = wv * 64;
    float4 acc[16];
#pragma unroll
    for (int r = 0; r < 16; ++r) acc[r] = make_float4(0,0,0,0);

#pragma unroll 1
    for (int s = 0; s < 16; ++s) {
        if (s < 15) {
            const int nb = (s + 1) & 1;
            const int ko = kbase + (s + 1) * 4;
#pragma unroll
            for (int j = 0; j < 4; ++j)
                async_load16(Cd + (size_t)(ko + j)*rowStride + ln*4,
                             BsF + wv*2048 + nb*1024 + j*256 + ln*4);
            asm volatile("s_waitcnt vmcnt(4)" ::: "memory");
        } else {
            asm volatile("s_waitcnt vmcnt(0)" ::: "memory");
        }
        __builtin_amdgcn_sched_barrier(0);
        const int cb = s & 1, kb = kbase + s * 4;
        const float* Bp = BsF + wv*2048 + cb*1024;
        const float4 b0v = *(const float4*)(Bp +   0 + ln*4);
        const float4 b1v = *(const float4*)(Bp + 256 + ln*4);
        const float4 b2v = *(const float4*)(Bp + 512 + ln*4);
        const float4 b3v = *(const float4*)(Bp + 768 + ln*4);
#pragma unroll
        for (int r = 0; r < 16; ++r) {
            const float4 a = *(const float4*)&As[r][kb];
            fma4(acc[r], a.x, b0v); fma4(acc[r], a.y, b1v);
            fma4(acc[r], a.z, b2v); fma4(acc[r], a.w, b3v);
        }
    }

    // two-phase cross-wave reduce through the (now dead) Bs region
#pragma unroll
    for (int ph = 0; ph < 2; ++ph) {
        float* my = BsF + wv * 2048;
#pragma unroll
        for (int r8 = 0; r8 < 8; ++r8)
            *(float4*)(my + r8*256 + ln*4) = acc[ph*8 + r8];
        __syncthreads();
#pragma unroll
        for (int i = 0; i < 2; ++i) {
            const int rr = wv*2 + i;
            float4 v        = *(const float4*)(BsF +        rr*256 + ln*4);
            const float4 p1 = *(const float4*)(BsF + 2048 + rr*256 + ln*4);
            const float4 p2 = *(const float4*)(BsF + 4096 + rr*256 + ln*4);
            const float4 p3 = *(const float4*)(BsF + 6144 + rr*256 + ln*4);
            v.x += p1.x + p2.x + p3.x; v.y += p1.y + p2.y + p3.y;
            v.z += p1.z + p2.z + p3.z; v.w += p1.w + p2.w + p3.w;
            const int r = ph*8 + rr;
            const int row = rowBase + mulLo*(r & 7) + 8*(r >> 3);
            *(float4*)(outP + (size_t)row*256 + ln*4) = v;
        }
        __syncthreads();
    }
}

// ---------------- K1: dense P3 table + dense U table -------------------------
__global__ __launch_bounds__(256, 3) void tables_kernel(
    const float* __restrict__ C0, const float* __restrict__ C1,
    const float* __restrict__ C2, const float* __restrict__ C3,
    const float* __restrict__ T, const float* __restrict__ C4t,
    float* __restrict__ P3, float* __restrict__ U)
{
    __shared__ __align__(16) struct {
        float v64[8][64]; float As[16][260]; float Bs[4][2][4][256];
    } u;                                       // 50.3 KB -> 3 blocks/CU
    const int t = threadIdx.x;
    const int ln = t & 63, wv = t >> 6;
    const int bx = blockIdx.x;
    float* BsF = &u.Bs[0][0][0][0];
    const int kbase = wv * 64;

    if (bx < 256) {
        // ---- P3 block: (d0, d2pair, d3); 16 rows = (d2sub, d1) ----
        const int d3 = bx & 7, d2p = (bx >> 3) & 3, d0 = bx >> 5;
        const float* Cd = C3 + d3 * 256;       // row k at Cd + k*2048

        // prefetch this wave's chunk-0 B rows
#pragma unroll
        for (int j = 0; j < 4; ++j)
            async_load16(Cd + (size_t)(kbase + j)*2048 + ln*4,
                         BsF + wv*2048 + j*256 + ln*4);

        // v64[d1][c] = sum_r C0[d0,r] * C1[r, d1, c]
#pragma unroll
        for (int j = 0; j < 2; ++j) {
            const int idx = t + 256*j, d1 = idx >> 6, c = idx & 63;
            float acc = 0.f;
#pragma unroll
            for (int r = 0; r < 8; ++r)
                acc = fmaf(C0[d0*8 + r], C1[r*512 + d1*64 + c], acc);
            u.v64[d1][c] = acc;
        }
        __syncthreads();

        // As[r][k] = sum_j v64[d1(r)][j] * C2[j, d2(r), k]
        // wave wv builds rows wv*4 .. wv*4+3 (all share d2 = d2p*2 + (wv>>1))
        {
            const int rbase = wv * 4;
            const int d2 = d2p*2 + (rbase >> 3);
            float4 a0 = make_float4(0,0,0,0), a1 = make_float4(0,0,0,0);
            float4 a2 = make_float4(0,0,0,0), a3 = make_float4(0,0,0,0);
#pragma unroll 8
            for (int j = 0; j < 64; ++j) {
                const float4 c2 = *(const float4*)(C2 + (size_t)j*2048 + d2*256 + ln*4);
                fma4(a0, u.v64[(rbase+0)&7][j], c2);
                fma4(a1, u.v64[(rbase+1)&7][j], c2);
                fma4(a2, u.v64[(rbase+2)&7][j], c2);
                fma4(a3, u.v64[(rbase+3)&7][j], c2);
            }
            *(float4*)&u.As[rbase+0][ln*4] = a0;
            *(float4*)&u.As[rbase+1][ln*4] = a1;
            *(float4*)&u.As[rbase+2][ln*4] = a2;
            *(float4*)&u.As[rbase+3][ln*4] = a3;
        }
        __syncthreads();                       // As + everyone's chunk0 ready

        // row = d0*512 + d1*64 + d2*8 + d3 with d1 = r&7, d2 = d2p*2 + (r>>3)
        kgemm16(Cd, 2048, u.As, BsF, P3, d0*512 + d2p*16 + d3, 64, ln, wv);
    } else {
        // ---- U block: (d4, qtile16); rows q = qtile*16 + 0..15 ----
        const int ub = bx - 256;
        const int qtile = ub & 31, d4 = ub >> 5;
        const float* Cd = C4t + (size_t)d4*65536; // row s5 at Cd + s5*256

        // prefetch this wave's chunk-0 B rows
#pragma unroll
        for (int j = 0; j < 4; ++j)
            async_load16(Cd + (size_t)(kbase + j)*256 + ln*4,
                         BsF + wv*2048 + j*256 + ln*4);
        // stage A rows from T: wave wv stages rows wv*4 .. wv*4+3
#pragma unroll
        for (int i = 0; i < 4; ++i) {
            const int r = wv*4 + i;
            async_load16(T + (size_t)(qtile*16 + r)*256 + ln*4, &u.As[r][ln*4]);
        }
        __syncthreads();                       // As + everyone's chunk0 ready

        // row = qtile*16 + r  (mulLo=1: (r&7) + 8*(r>>3) == r)
        kgemm16(Cd, 256, u.As, BsF, U, d4*512 + qtile*16, 1, ln, wv);
    }
}

// ---------------- K2: per-sample dot(P3 row, U row), 2 samples/wave ----------
__global__ __launch_bounds__(256) void final_kernel(
    const float* __restrict__ P3, const float* __restrict__ U,
    const int* __restrict__ coords, int n, float* __restrict__ out)
{
    const int ln = threadIdx.x & 63, wv = threadIdx.x >> 6;
    const int s0 = blockIdx.x * 8 + wv * 2;

    float p[2] = {0.f, 0.f};
    int valid[2];
#pragma unroll
    for (int i = 0; i < 2; ++i) {
        const int s = s0 + i;
        valid[i] = (s < n);
        if (valid[i]) {
            const int x = coords[3*s], y = coords[3*s+1], z = coords[3*s+2];
            const int a  = digit_of(x,y,z,7)*512 + digit_of(x,y,z,6)*64
                         + digit_of(x,y,z,5)*8  + digit_of(x,y,z,4);
            const int d4 = digit_of(x,y,z,3);
            const int q  = digit_of(x,y,z,2)*64 + digit_of(x,y,z,1)*8
                         + digit_of(x,y,z,0);
            const float4 p4 = *(const float4*)(P3 + (size_t)a*256 + ln*4);
            const float4 u4 = *(const float4*)(U + (size_t)(d4*512 + q)*256 + ln*4);
            p[i] = fmaf(p4.x, u4.x, fmaf(p4.y, u4.y,
                   fmaf(p4.z, u4.z, p4.w * u4.w)));
        }
    }
#pragma unroll
    for (int m = 1; m <= 32; m <<= 1) {
        p[0] += __shfl_xor(p[0], m);
        p[1] += __shfl_xor(p[1], m);
    }
    if (ln == 0) {
        if (valid[0]) out[s0]     = p[0];
        if (valid[1]) out[s0 + 1] = p[1];
    }
}

extern "C" void kernel_launch(void* const* d_in, const int* in_sizes, int n_in,
                              void* d_out, int out_size, void* d_ws, size_t ws_size,
                              hipStream_t stream) {
    const float* C0 = (const float*)d_in[0];
    const float* C1 = (const float*)d_in[1];
    const float* C2 = (const float*)d_in[2];
    const float* C3 = (const float*)d_in[3];
    const float* C4 = (const float*)d_in[4];
    const float* C5 = (const float*)d_in[5];
    const float* C6 = (const float*)d_in[6];
    const float* C7 = (const float*)d_in[7];
    const int* coords = (const int*)d_in[8];
    float* out = (float*)d_out;

    const int n = in_sizes[8] / 3;

    // workspace (~11 MB)
    float* P3  = (float*)d_ws;                 // 4096*256
    float* U   = P3  + 4096*256;               // 4096*256
    float* Tt  = U   + 4096*256;               // 512*256
    float* C4t = Tt  + 512*256;                // 8*256*256

    prep_kernel<<<96, 256, 0, stream>>>(C4, C5, C6, C7, Tt, C4t);
    tables_kernel<<<512, 256, 0, stream>>>(C0, C1, C2, C3, Tt, C4t, P3, U);
    final_kernel<<<(n + 7) / 8, 256, 0, stream>>>(P3, U, coords, n, out);
}